// Round 12
// baseline (161.695 us; speedup 1.0000x reference)
//
#include <hip/hip_runtime.h>
#include <float.h>

// EdgeConv: B=4, N=4096, Fin=64, Fout=64, K=20
// out[b,n,o] = u[b,n,o] + max_{m in knn20(n)} v[b,m,o]
//   u = x.(W1-W2)^T + bias ; v = x.W2^T
// knn on d = sq[n] + sq[m] - 2 x_n.x_m (>=0), self excluded.
//
// R18 = R17 (K3 select2 2-rows/wave: every dispatch <=51 us, kept) +
// paired-dword key stores in K2. K2 evidence: WRITE 158 MB for a 128 MB
// array (1.23x amplification), 16x 2B-per-lane stores/j each covering
// only 64 B/row. Fix: shfl_xor(.,1) exchange so lane 2k packs cols
// (2k,2k+1) into one u32; even lanes store even-e rows, odd lanes odd-e
// rows IN THE SAME instruction -> 8 stores/j, 256 B dense each. All
// register indices compile-time (parity via cndmask-selects). Numerics
// unchanged (same key values, same addresses).

constexpr int Bb = 4, Nn = 4096, Ff = 64, Kk = 20;

typedef __attribute__((ext_vector_type(8))) short bf16x8;
typedef __attribute__((ext_vector_type(16))) float f32x16;

__device__ inline unsigned int bf16rn(float f) {
  unsigned int u = __float_as_uint(f);
  return (u + 0x7fffu + ((u >> 16) & 1u)) >> 16;
}

// ---------------- K1: u, v, sq, xhi, xlo (swizzled) ----------------
constexpr int RT1 = 16;  // rows per block

__global__ __launch_bounds__(256) void uv_kernel2(
    const float* __restrict__ x, const float* __restrict__ W,
    const float* __restrict__ bvec, float* __restrict__ u,
    float* __restrict__ v, float* __restrict__ sq,
    unsigned short* __restrict__ xhi, unsigned short* __restrict__ xlo) {
  __shared__ __align__(16) float4 Ws[64 * 33];   // W row o at granules [33o,33o+32)
  __shared__ __align__(16) float4 xs[RT1 * 16];  // x row r at [16r..)
  const int t = threadIdx.x, l = t & 63, w = t >> 6;
  const int bn0 = blockIdx.x * RT1;
  #pragma unroll
  for (int i = 0; i < 8; i++) {
    int f = t + 256 * i;  // f4 index into W (64 rows x 32 f4)
    Ws[(f >> 5) * 33 + (f & 31)] = ((const float4*)W)[f];
  }
  xs[t] = ((const float4*)x)[bn0 * 16 + t];
  __syncthreads();
  // bf16 hi/lo split -> MFMA-fragment-swizzled layout
  #pragma unroll
  for (int i = 0; i < 4; i++) {
    int idx = t + 256 * i;   // 0..1023 within block's 16 rows
    int nloc = idx >> 6;     // row within block
    int k = idx & 63;        // channel
    float val = ((const float*)xs)[idx];
    unsigned int hb = bf16rn(val);
    float fhi = __uint_as_float(hb << 16);
    unsigned int lb = bf16rn(val - fhi);
    int ng = bn0 + nloc;  // global flat row (batch-local swizzle folds in)
    size_t flat = ((size_t)(ng >> 5) << 11) + ((size_t)(k >> 4) << 9) +
                  ((size_t)((k >> 3) & 1) << 8) + ((size_t)(ng & 31) << 3) +
                  (size_t)(k & 7);
    xhi[flat] = (unsigned short)hb;
    xlo[flat] = (unsigned short)lb;
  }
  // sq for rows 4w..4w+3
  #pragma unroll
  for (int i = 0; i < 4; i++) {
    int r = 4 * w + i;
    float val = ((const float*)&xs[r * 16])[l];
    float s = val * val;
    #pragma unroll
    for (int d = 32; d; d >>= 1) s += __shfl_xor(s, d, 64);
    if (l == 0) sq[bn0 + r] = s;
  }
  const int o = l;
  float ua[4] = {0.f, 0.f, 0.f, 0.f}, va[4] = {0.f, 0.f, 0.f, 0.f};
  #pragma unroll
  for (int c = 0; c < 16; c++) {
    float4 w1 = Ws[o * 33 + c];
    float4 w2 = Ws[o * 33 + 16 + c];
    float4 wd;
    wd.x = w1.x - w2.x; wd.y = w1.y - w2.y;
    wd.z = w1.z - w2.z; wd.w = w1.w - w2.w;
    #pragma unroll
    for (int i = 0; i < 4; i++) {
      float4 xv = xs[(4 * w + i) * 16 + c];
      ua[i] += xv.x * wd.x + xv.y * wd.y + xv.z * wd.z + xv.w * wd.w;
      va[i] += xv.x * w2.x + xv.y * w2.y + xv.z * w2.z + xv.w * w2.w;
    }
  }
  float bo = bvec[o];
  #pragma unroll
  for (int i = 0; i < 4; i++) {
    size_t row = (size_t)(bn0 + 4 * w + i);
    u[row * 64 + o] = ua[i] + bo;
    v[row * 64 + o] = va[i];
  }
}

// ---------------- K2: MFMA distance keys, paired-dword stores ----------
// Per wave: 32 n-rows x 256 m-cols. Block = 4 waves. Grid 2048 blocks.
// C/D: col=lane&31, row=(reg&3)+8*(reg>>2)+4*(lane>>5) [m74/m101].

__global__ __launch_bounds__(256) void key_mfma_kernel(
    const unsigned short* __restrict__ xhi,
    const unsigned short* __restrict__ xlo, const float* __restrict__ sq,
    unsigned short* __restrict__ keys) {
  const int t = threadIdx.x, l = t & 63, w = t >> 6;
  const int blk = blockIdx.x;
  const int b = blk >> 9;
  const int r = blk & 511;
  const int n_base = (r >> 2) * 32;
  const int m0w = (r & 3) * 1024 + w * 256;
  const int col = l & 31, half = l >> 5;
  const int parity = l & 1;

  const unsigned short* xhb = xhi + (size_t)b * Nn * Ff;
  const unsigned short* xlb = xlo + (size_t)b * Nn * Ff;
  const float* sqb = sq + b * Nn;

  bf16x8 Ahi[4], Alo[4];
  #pragma unroll
  for (int ks = 0; ks < 4; ks++) {
    size_t off = ((size_t)((n_base >> 5) * 4 + ks) << 9) + ((size_t)l << 3);
    Ahi[ks] = *(const bf16x8*)(xhb + off);
    Alo[ks] = *(const bf16x8*)(xlb + off);
  }
  float sqn_r[16];
  #pragma unroll
  for (int e = 0; e < 16; e++) {
    int row = (e & 3) + 8 * (e >> 2) + 4 * half;
    sqn_r[e] = sqb[n_base + row];
  }

  for (int j = 0; j < 8; ++j) {
    const int m0 = m0w + 32 * j;
    const int mblk = m0 >> 5;
    bf16x8 Bhi[4], Blo[4];
    #pragma unroll
    for (int ks = 0; ks < 4; ks++) {
      size_t off = ((size_t)(mblk * 4 + ks) << 9) + ((size_t)l << 3);
      Bhi[ks] = *(const bf16x8*)(xhb + off);
      Blo[ks] = *(const bf16x8*)(xlb + off);
    }
    f32x16 acc = {0.f, 0.f, 0.f, 0.f, 0.f, 0.f, 0.f, 0.f,
                  0.f, 0.f, 0.f, 0.f, 0.f, 0.f, 0.f, 0.f};
    #pragma unroll
    for (int ks = 0; ks < 4; ks++) {
      acc = __builtin_amdgcn_mfma_f32_32x32x16_bf16(Ahi[ks], Bhi[ks], acc, 0, 0, 0);
      acc = __builtin_amdgcn_mfma_f32_32x32x16_bf16(Ahi[ks], Blo[ks], acc, 0, 0, 0);
      acc = __builtin_amdgcn_mfma_f32_32x32x16_bf16(Alo[ks], Bhi[ks], acc, 0, 0, 0);
    }
    const int m = m0 + col;
    const float sm = sqb[m];
    // compute all 16 keys first
    unsigned int k16[16];
    #pragma unroll
    for (int e = 0; e < 16; e++) {
      int row = (e & 3) + 8 * (e >> 2) + 4 * half;
      int n = n_base + row;
      float d = fmaxf(sqn_r[e] + sm - 2.0f * acc[e], 0.f);
      unsigned int key = __float_as_uint(d) >> 15;
      if (m == n) key = 0xFFFFu;
      k16[e] = key;
    }
    // neighbor-lane exchange (all lanes execute every shfl)
    unsigned int prt[16];
    #pragma unroll
    for (int e = 0; e < 16; e++)
      prt[e] = (unsigned int)__shfl_xor((int)k16[e], 1, 64);
    // paired-dword stores: slot i -> even lanes store row r(2i) with
    // word (own|part<<16), odd lanes store row r(2i+1) with (part|own<<16).
    // All 64 lanes active per store: 256 B dense (4 rows x 64 B).
    const unsigned int mpair = (unsigned int)(m0 + (col & ~1));
    #pragma unroll
    for (int i = 0; i < 8; i++) {
      unsigned int we = k16[2 * i] | (prt[2 * i] << 16);        // even-lane word
      unsigned int wo = prt[2 * i + 1] | (k16[2 * i + 1] << 16);// odd-lane word
      unsigned int word = parity ? wo : we;
      int re = ((2 * i) & 3) + 8 * ((2 * i) >> 2) + 4 * half;
      int ro = ((2 * i + 1) & 3) + 8 * ((2 * i + 1) >> 2) + 4 * half;
      int row = parity ? ro : re;
      int n = n_base + row;
      ((unsigned int*)keys)[((((size_t)(b * Nn + n)) << 12) + mpair) >> 1] = word;
    }
  }
}

// ---------------- K3: 2 rows/wave histogram select + exact top-20 -------
// Grid 2048 blocks x 256 thr; wave w handles rows blk*8+2w, blk*8+2w+1.
// Two independent latency chains interleaved per wave. (R17: <=51 us.)
__global__ __launch_bounds__(256) void select2_kernel(
    const float* __restrict__ x, const unsigned short* __restrict__ keys,
    const float* __restrict__ u, const float* __restrict__ v,
    float* __restrict__ out) {
  __shared__ unsigned int histS[8][256];
  __shared__ int candS[8][64];
  __shared__ unsigned long long keyS[8][64];
  const int t = threadIdx.x, l = t & 63, w = t >> 6;
  const int rowu0 = __builtin_amdgcn_readfirstlane(blockIdx.x * 8 + w * 2);
  const int rowu1 = rowu0 + 1;

  uint4 kv[2][8];
  {
    const uint4* kr0 = (const uint4*)(keys + (size_t)rowu0 * Nn);
    const uint4* kr1 = (const uint4*)(keys + (size_t)rowu1 * Nn);
    #pragma unroll
    for (int j = 0; j < 8; j++) {
      kv[0][j] = kr0[j * 64 + l];
      kv[1][j] = kr1[j * 64 + l];
    }
  }
  // zero this wave's two hist rows (same-wave LDS: in-order, no barrier)
  #pragma unroll
  for (int i = 0; i < 4; i++) {
    histS[w * 2 + 0][4 * l + i] = 0u;
    histS[w * 2 + 1][4 * l + i] = 0u;
  }

  auto countLE = [&](int rr, int mid) -> int {
    int c = 0;
    #pragma unroll
    for (int j = 0; j < 8; j++) {
      unsigned int a0 = kv[rr][j].x, a1 = kv[rr][j].y;
      unsigned int a2 = kv[rr][j].z, a3 = kv[rr][j].w;
      c += ((int)(a0 & 0xffffu) <= mid) + ((int)(a0 >> 16) <= mid);
      c += ((int)(a1 & 0xffffu) <= mid) + ((int)(a1 >> 16) <= mid);
      c += ((int)(a2 & 0xffffu) <= mid) + ((int)(a2 >> 16) <= mid);
      c += ((int)(a3 & 0xffffu) <= mid) + ((int)(a3 >> 16) <= mid);
    }
    #pragma unroll
    for (int d2 = 1; d2 < 64; d2 <<= 1) c += __shfl_xor(c, d2, 64);
    return c;
  };

  // wave-wide min per row (two butterfly chains interleaved)
  unsigned int mn[2];
  #pragma unroll
  for (int rr = 0; rr < 2; rr++) {
    unsigned int m_ = 0xffffffffu;
    #pragma unroll
    for (int j = 0; j < 8; j++) {
      unsigned int a0 = kv[rr][j].x, a1 = kv[rr][j].y;
      unsigned int a2 = kv[rr][j].z, a3 = kv[rr][j].w;
      m_ = min(m_, min(min(a0 & 0xffffu, a0 >> 16), min(a1 & 0xffffu, a1 >> 16)));
      m_ = min(m_, min(min(a2 & 0xffffu, a2 >> 16), min(a3 & 0xffffu, a3 >> 16)));
    }
    mn[rr] = m_;
  }
  #pragma unroll
  for (int d2 = 1; d2 < 64; d2 <<= 1) {
    mn[0] = min(mn[0], (unsigned int)__shfl_xor((int)mn[0], d2, 64));
    mn[1] = min(mn[1], (unsigned int)__shfl_xor((int)mn[1], d2, 64));
  }

  // histograms (window 256 above row min; rel>=256 skipped: can't matter
  // unless <20 keys that close -> gallop fallback)
  #pragma unroll
  for (int rr = 0; rr < 2; rr++) {
    #pragma unroll
    for (int j = 0; j < 8; j++) {
      unsigned int a[4] = {kv[rr][j].x, kv[rr][j].y, kv[rr][j].z, kv[rr][j].w};
      #pragma unroll
      for (int e = 0; e < 4; e++) {
        unsigned int r0 = (a[e] & 0xffffu) - mn[rr];
        unsigned int r1 = (a[e] >> 16) - mn[rr];
        if (r0 < 256u) atomicAdd(&histS[w * 2 + rr][r0], 1u);
        if (r1 < 256u) atomicAdd(&histS[w * 2 + rr][r1], 1u);
      }
    }
  }

  // prefix scan + threshold pick per row (two chains interleaved)
  unsigned int s_[2][4], ls_[2], cum_[2];
  #pragma unroll
  for (int rr = 0; rr < 2; rr++) {
    #pragma unroll
    for (int i = 0; i < 4; i++) s_[rr][i] = histS[w * 2 + rr][4 * l + i];
    ls_[rr] = s_[rr][0] + s_[rr][1] + s_[rr][2] + s_[rr][3];
    cum_[rr] = ls_[rr];
  }
  #pragma unroll
  for (int d2 = 1; d2 < 64; d2 <<= 1) {
    unsigned int o0 = (unsigned int)__shfl_up((int)cum_[0], d2, 64);
    unsigned int o1 = (unsigned int)__shfl_up((int)cum_[1], d2, 64);
    cum_[0] += (l >= d2) ? o0 : 0u;
    cum_[1] += (l >= d2) ? o1 : 0u;
  }
  int hc[2];
  #pragma unroll
  for (int rr = 0; rr < 2; rr++) {
    unsigned int excl = cum_[rr] - ls_[rr];
    unsigned int c0 = excl + s_[rr][0], c1 = c0 + s_[rr][1], c2 = c1 + s_[rr][2];
    unsigned long long bal = __ballot(cum_[rr] >= (unsigned int)Kk);
    if (bal != 0ull) {
      int b_loc = (c0 >= (unsigned)Kk) ? 0 : (c1 >= (unsigned)Kk) ? 1
                : (c2 >= (unsigned)Kk) ? 2 : 3;
      int flane = __ffsll(bal) - 1;
      int hi_rel = __shfl(4 * l + b_loc, flane, 64);
      hc[rr] = (int)mn[rr] + hi_rel + 1;  // +1 quantum margin (approx keys)
    } else {
      // fallback: gallop up from min (BOUNDED), then bisect (rare)
      int lo = (int)mn[rr] - 1;
      int hi = (int)mn[rr] + 64;
      if (hi > 65534) hi = 65534;
      int c = countLE(rr, hi);
      int step = 128;
      while (c < Kk && hi < 65534) {
        lo = hi;
        hi += step;
        if (hi > 65534) hi = 65534;
        step <<= 1;
        c = countLE(rr, hi);
      }
      while (c > 44 && hi - lo > 1) {
        int mid = (lo + hi) >> 1;
        int cm = countLE(rr, mid);
        if (cm >= Kk) { hi = mid; c = cm; } else { lo = mid; }
      }
      hc[rr] = hi + 1;
    }
  }

  // per-lane-count + scan compaction (R16-verified form), both rows
  int myc[2];
  #pragma unroll
  for (int rr = 0; rr < 2; rr++) {
    int c = 0;
    #pragma unroll
    for (int j = 0; j < 8; j++) {
      unsigned int a0 = kv[rr][j].x, a1 = kv[rr][j].y;
      unsigned int a2 = kv[rr][j].z, a3 = kv[rr][j].w;
      c += ((int)(a0 & 0xffffu) <= hc[rr]) + ((int)(a0 >> 16) <= hc[rr]);
      c += ((int)(a1 & 0xffffu) <= hc[rr]) + ((int)(a1 >> 16) <= hc[rr]);
      c += ((int)(a2 & 0xffffu) <= hc[rr]) + ((int)(a2 >> 16) <= hc[rr]);
      c += ((int)(a3 & 0xffffu) <= hc[rr]) + ((int)(a3 >> 16) <= hc[rr]);
    }
    myc[rr] = c;
  }
  int incl0 = myc[0], incl1 = myc[1];
  #pragma unroll
  for (int d2 = 1; d2 < 64; d2 <<= 1) {
    int o0 = __shfl_up(incl0, d2, 64);
    int o1 = __shfl_up(incl1, d2, 64);
    incl0 += (l >= d2) ? o0 : 0;
    incl1 += (l >= d2) ? o1 : 0;
  }
  int C[2];
  C[0] = __shfl(incl0, 63);
  C[1] = __shfl(incl1, 63);
  int off[2] = {incl0 - myc[0], incl1 - myc[1]};
  #pragma unroll
  for (int rr = 0; rr < 2; rr++) {
    int o = off[rr];
    #pragma unroll
    for (int j = 0; j < 8; j++) {
      unsigned int a[4] = {kv[rr][j].x, kv[rr][j].y, kv[rr][j].z, kv[rr][j].w};
      #pragma unroll
      for (int e = 0; e < 4; e++) {
        int base = ((j * 64 + l) * 4 + e) * 2;
        if ((int)(a[e] & 0xffffu) <= hc[rr]) {
          if (o < 64) candS[w * 2 + rr][o] = base;
          o++;
        }
        if ((int)(a[e] >> 16) <= hc[rr]) {
          if (o < 64) candS[w * 2 + rr][o] = base + 1;
          o++;
        }
      }
    }
    if (C[rr] > 64) C[rr] = 64;
  }

  // exact fp32 rerank, both rows (x-gathers interleave -> MLP)
  unsigned long long key64[2];
  #pragma unroll
  for (int rr = 0; rr < 2; rr++) {
    const int rowu = rr ? rowu1 : rowu0;
    const int b = rowu >> 12, n = rowu & (Nn - 1);
    const float4* xb4 = (const float4*)(x + (size_t)b * Nn * Ff);
    key64[rr] = 0xFFFFFFFF00000000ull | (unsigned int)l;
    if (l < C[rr]) {
      int mI = candS[w * 2 + rr][l];
      const float4* xmf = xb4 + (size_t)mI * 16;
      float ds = 0.f;
      #pragma unroll
      for (int cc = 0; cc < 16; cc++) {
        float4 a = xb4[(size_t)n * 16 + cc];  // wave-uniform
        float4 bb = xmf[cc];
        float dx = a.x - bb.x, dy = a.y - bb.y, dz = a.z - bb.z,
              dw2 = a.w - bb.w;
        ds += dx * dx + dy * dy + dz * dz + dw2 * dw2;
      }
      if (mI == n) ds = FLT_MAX;  // belt-and-braces
      key64[rr] =
          ((unsigned long long)__float_as_uint(ds) << 32) | (unsigned int)mI;
    }
    keyS[w * 2 + rr][l] = key64[rr];
  }
  // rank-select top-20 per row (keys unique: distinct m / lane sentinels)
  #pragma unroll
  for (int rr = 0; rr < 2; rr++) {
    const unsigned long long* kws = &keyS[w * 2 + rr][0];
    unsigned long long k64 = key64[rr];
    int rank = 0;
    #pragma unroll
    for (int q = 0; q < 64; q += 4) {
      rank += (kws[q] < k64) + (kws[q + 1] < k64) +
              (kws[q + 2] < k64) + (kws[q + 3] < k64);
    }
    if (rank < Kk)
      candS[w * 2 + rr][rank] = (int)(k64 & 0xffffffffu) & (Nn - 1);
  }

  // v-gathers (40 independent loads) + fmax trees + outputs
  #pragma unroll
  for (int rr = 0; rr < 2; rr++) {
    const int rowu = rr ? rowu1 : rowu0;
    const int b = rowu >> 12;
    const float* vb = v + (size_t)b * Nn * Ff;
    const size_t oidx = (size_t)rowu * 64 + l;
    float uo = u[oidx];
    float vv[Kk];
    #pragma unroll
    for (int i = 0; i < Kk; i++) {
      int mI = candS[w * 2 + rr][i];
      vv[i] = vb[(size_t)mI * 64 + l];
    }
    float vmax = vv[0];
    #pragma unroll
    for (int i = 1; i < Kk; i++) vmax = fmaxf(vmax, vv[i]);
    out[oidx] = uo + vmax;
  }
}

// ---------------- R2 fallback knn (verified) ----------------
constexpr int RTF = 4;
constexpr int MTF = 64;
constexpr int TPADF = 17;
constexpr int CCAPF = 64;

__global__ __launch_bounds__(256) void knn_kernel(
    const float* __restrict__ x, const float* __restrict__ sq,
    const float* __restrict__ u, const float* __restrict__ v,
    float* __restrict__ out) {
  __shared__ __align__(16) float4 tileS[MTF * TPADF];
  __shared__ __align__(16) unsigned short keysS[RTF * Nn];
  __shared__ int candS[RTF * CCAPF];
  __shared__ int ccntS[RTF];
  const int t = threadIdx.x;
  const int l = t & 63, w = t >> 6;
  const int q = l & 15, g = l >> 4;
  const int bn0 = blockIdx.x * RTF;
  const int b = bn0 >> 12;
  const int n0 = bn0 & (Nn - 1);
  const float4* xb4 = (const float4*)(x + (size_t)b * Nn * Ff);
  const float* sqb = sq + b * Nn;
  if (t < RTF) ccntS[t] = 0;
  float4 xnq[RTF][4];
  #pragma unroll
  for (int r = 0; r < RTF; r++)
    #pragma unroll
    for (int c = 0; c < 4; c++) xnq[r][c] = xb4[(n0 + r) * 16 + 4 * g + c];
  const float sn = sqb[n0 + g];
  const int selfm = n0 + g;
  for (int T = 0; T < Nn / MTF; ++T) {
    __syncthreads();
    #pragma unroll
    for (int i = 0; i < 4; i++) {
      int f = t + 256 * i;
      tileS[(f >> 4) * TPADF + (f & 15)] = xb4[T * 1024 + f];
    }
    __syncthreads();
    const int mrow = 16 * w + q;
    const float4* xmp = &tileS[mrow * TPADF + 4 * g];
    float4 xm0 = xmp[0], xm1 = xmp[1], xm2 = xmp[2], xm3 = xmp[3];
    float dot[RTF];
    #pragma unroll
    for (int r = 0; r < RTF; r++) {
      float4 a0 = xnq[r][0], a1 = xnq[r][1], a2 = xnq[r][2], a3 = xnq[r][3];
      dot[r] = a0.x * xm0.x + a0.y * xm0.y + a0.z * xm0.z + a0.w * xm0.w +
               a1.x * xm1.x + a1.y * xm1.y + a1.z * xm1.z + a1.w * xm1.w +
               a2.x * xm2.x + a2.y * xm2.y + a2.z * xm2.z + a2.w * xm2.w +
               a3.x * xm3.x + a3.y * xm3.y + a3.z * xm3.z + a3.w * xm3.w;
    }
    #pragma unroll
    for (int r = 0; r < RTF; r++) {
      dot[r] += __shfl_xor(dot[r], 16, 64);
      dot[r] += __shfl_xor(dot[r], 32, 64);
    }
    float dg = (g == 0) ? dot[0] : (g == 1) ? dot[1] : (g == 2) ? dot[2] : dot[3];
    int m = T * MTF + mrow;
    float d = fmaxf(fmaf(-2.f, dg, sqb[m] + sn), 0.f);
    unsigned int key = __float_as_uint(d) >> 15;
    if (m == selfm) key = 0xFFFFu;
    keysS[g * Nn + m] = (unsigned short)key;
  }
  __syncthreads();
  const unsigned int* kp = (const unsigned int*)&keysS[w * Nn];
  int lo = -1, hi = 65535, cntHi = Nn;
  while (cntHi > 48 && hi - lo > 1) {
    int mid = (lo + hi) >> 1;
    unsigned int midu = (unsigned int)mid;
    int c = 0;
    #pragma unroll
    for (int cc = 0; cc < 8; ++cc) {
      int rc = (cc + l) & 7;
      uint4 k4 = *(const uint4*)(kp + l * 32 + rc * 4);
      c += ((k4.x & 0xffffu) <= midu) + ((k4.x >> 16) <= midu);
      c += ((k4.y & 0xffffu) <= midu) + ((k4.y >> 16) <= midu);
      c += ((k4.z & 0xffffu) <= midu) + ((k4.z >> 16) <= midu);
      c += ((k4.w & 0xffffu) <= midu) + ((k4.w >> 16) <= midu);
    }
    #pragma unroll
    for (int d2 = 1; d2 < 64; d2 <<= 1) c += __shfl_xor(c, d2, 64);
    if (c >= Kk) { hi = mid; cntHi = c; } else { lo = mid; }
  }
  {
    unsigned int hu = (unsigned int)hi;
    #pragma unroll
    for (int cc = 0; cc < 8; ++cc) {
      int rc = (cc + l) & 7;
      uint4 k4 = *(const uint4*)(kp + l * 32 + rc * 4);
      unsigned int ks[4] = {k4.x, k4.y, k4.z, k4.w};
      #pragma unroll
      for (int uu = 0; uu < 4; ++uu) {
        #pragma unroll
        for (int hh = 0; hh < 2; ++hh) {
          unsigned int kvv = hh ? (ks[uu] >> 16) : (ks[uu] & 0xffffu);
          if (kvv <= hu) {
            int slot = atomicAdd(&ccntS[w], 1);
            if (slot < CCAPF) candS[w * CCAPF + slot] = l * 64 + (rc * 4 + uu) * 2 + hh;
          }
        }
      }
    }
  }
  __syncthreads();
  const int n = n0 + w;
  const int C = min(cntHi, CCAPF);
  unsigned long long key64 = ~0ULL;
  if (l < C) {
    int mI = candS[w * CCAPF + l];
    const float4* xmf = xb4 + mI * 16;
    float ds = 0.f;
    #pragma unroll
    for (int c = 0; c < 16; c++) {
      float4 a = xb4[n * 16 + c];
      float4 bb = xmf[c];
      float dx = a.x - bb.x, dy = a.y - bb.y, dz = a.z - bb.z, dw2 = a.w - bb.w;
      ds += dx * dx + dy * dy + dz * dz + dw2 * dw2;
    }
    key64 = ((unsigned long long)__float_as_uint(ds) << 32) | (unsigned int)mI;
  }
  float vmax = -FLT_MAX;
  const float* vb = v + (size_t)b * Nn * Ff;
  #pragma unroll
  for (int it = 0; it < Kk; ++it) {
    unsigned long long kmin = key64;
    #pragma unroll
    for (int d2 = 1; d2 < 64; d2 <<= 1) {
      unsigned long long o =
          (unsigned long long)__shfl_xor((long long)kmin, d2, 64);
      kmin = (o < kmin) ? o : kmin;
    }
    int mI = (int)(kmin & 0xffffffffu) & (Nn - 1);
    vmax = fmaxf(vmax, vb[(size_t)mI * 64 + l]);
    if (key64 == kmin) key64 = ~0ULL;
  }
  const size_t oidx = (size_t)(bn0 + w) * 64 + l;
  out[oidx] = u[oidx] + vmax;
}

extern "C" void kernel_launch(void* const* d_in, const int* in_sizes, int n_in,
                              void* d_out, int out_size, void* d_ws,
                              size_t ws_size, hipStream_t stream) {
  const float* x = (const float*)d_in[0];
  const float* W = (const float*)d_in[1];
  const float* bvec = (const float*)d_in[2];
  float* u = (float*)d_ws;                           // 4 MB
  float* v = u + (size_t)Bb * Nn * Ff;               // 4 MB
  float* sq = v + (size_t)Bb * Nn * Ff;              // 64 KB
  unsigned short* xhi = (unsigned short*)(sq + (size_t)Bb * Nn);  // 2 MB
  unsigned short* xlo = xhi + (size_t)Bb * Nn * Ff;               // 2 MB
  unsigned short* keys = xlo + (size_t)Bb * Nn * Ff;              // 128 MB
  float* out = (float*)d_out;
  const size_t need = (size_t)Bb * Nn * Ff * 4 * 2 + (size_t)Bb * Nn * 4 +
                      (size_t)Bb * Nn * Ff * 2 * 2 + (size_t)Bb * Nn * Nn * 2;

  uv_kernel2<<<Bb * Nn / RT1, 256, 0, stream>>>(x, W, bvec, u, v, sq, xhi, xlo);
  if (ws_size >= need) {
    // 4 batches x 128 n-tiles x 4 m-quarters = 2048 blocks
    key_mfma_kernel<<<Bb * Nn / 8, 256, 0, stream>>>(xhi, xlo, sq, keys);
    // 2048 blocks x 8 rows (2 per wave)
    select2_kernel<<<Bb * Nn / 8, 256, 0, stream>>>(x, keys, u, v, out);
  } else {
    knn_kernel<<<Bb * Nn / RTF, 256, 0, stream>>>(x, sq, u, v, out);
  }
}